// Round 6
// baseline (2027.862 us; speedup 1.0000x reference)
//
#include <hip/hip_runtime.h>
#include <stdint.h>

#define D 4096

typedef __attribute__((ext_vector_type(8))) short bf16x8;
typedef __attribute__((ext_vector_type(4))) float f32x4;

__device__ __forceinline__ ushort f2bf(float f) {
    uint32_t u = __float_as_uint(f);
    uint32_t r = (u + 0x7FFFu + ((u >> 16) & 1u)) >> 16;
    return (ushort)r;
}
__device__ __forceinline__ float bf2f(ushort h) {
    return __uint_as_float(((uint32_t)h) << 16);
}
__device__ __forceinline__ float sgnf(float z) {
    return (z > 0.f) ? 1.f : ((z < 0.f) ? -1.f : 0.f);
}
__device__ __forceinline__ void split3(float v, ushort& h, ushort& m, ushort& l) {
    h = f2bf(v);
    float r1 = v - bf2f(h);
    m = f2bf(r1);
    l = f2bf(r1 - bf2f(m));
}
__device__ __forceinline__ uint4 pack8(const ushort* s) {
    uint4 u;
    u.x = (uint)s[0] | ((uint)s[1] << 16);
    u.y = (uint)s[2] | ((uint)s[3] << 16);
    u.z = (uint)s[4] | ((uint)s[5] << 16);
    u.w = (uint)s[6] | ((uint)s[7] << 16);
    return u;
}

// ---- forward GEMV: bit-exact emulation of numpy-f32 (OpenBLAS AVX2 sgemv_t) ----
// DO NOT TOUCH — bit-exactness of z1/z2/z3 vs the reference is load-bearing.
__global__ __launch_bounds__(256) void gemv_blas8(const float* __restrict__ W,
                                                  const float* __restrict__ v,
                                                  const float* __restrict__ bias,
                                                  float* __restrict__ z,
                                                  float* __restrict__ act, int doAct) {
    int gid = blockIdx.x * 256 + threadIdx.x;
    int row = gid >> 3;
    int l = gid & 7;
    const float* wr = W + (size_t)row * D;
    float acc = 0.f;
    for (int k = l; k < D; k += 8) acc = fmaf(wr[k], v[k], acc);
    float b = acc + __shfl_xor(acc, 4);
    float c = b + __shfl_xor(b, 1);
    float s = c + __shfl_xor(c, 2);
    if (l == 0) {
        z[row] = s;
        if (doAct) act[row] = fmaxf(s + bias[row], 0.f);
    }
}

__global__ __launch_bounds__(256) void vecprep32(const float* __restrict__ z1,
                                                 const float* __restrict__ z2,
                                                 const float* __restrict__ z3,
                                                 const float* __restrict__ a1,
                                                 const float* __restrict__ a2,
                                                 const float* __restrict__ b3,
                                                 float* __restrict__ out,
                                                 float* __restrict__ s3,
                                                 float* __restrict__ g2,
                                                 float* __restrict__ g1) {
    int i = blockIdx.x * 256 + threadIdx.x;
    float z3v = z3[i];
    float o = z3v + b3[i];
    out[i] = o;
    s3[i] = o / (z3v + 1e-9f * sgnf(z3v));
    float z2v = z2[i];
    g2[i] = a2[i] / (z2v + 1e-9f * sgnf(z2v));
    float z1v = z1[i];
    g1[i] = a1[i] / (z1v + 1e-9f * sgnf(z1v));
}

// ================= blocked-plane machinery =================
// Blocked plane layout (per plane, 32 MB): index = ((bi*128 + kt)*512 + cell)*8 ushorts,
// cell = b*64 + r*4 + g; element (row = bi*128 + b*16 + r, k = kt*32 + g*8 + j).
// This is exactly MFMA fragment order: wave reads cell run (r*4+g) = dense 16B/lane.

// prepA1: A = s3[row] * W3[row][k] * g2[k], split h/m/l into blocked planes
__global__ __launch_bounds__(256) void prepA1(const float* __restrict__ W3,
                                              const float* __restrict__ s3,
                                              const float* __restrict__ g2,
                                              ushort* __restrict__ Ph,
                                              ushort* __restrict__ Pm,
                                              ushort* __restrict__ Pl) {
    size_t tid = (size_t)blockIdx.x * 256 + threadIdx.x;
    int cell = (int)(tid & 511);
    int kt = (int)((tid >> 9) & 127);
    int bi = (int)(tid >> 16);
    int b = cell >> 6, rg = cell & 63, r = rg >> 2, g = rg & 3;
    int row = bi * 128 + b * 16 + r;
    int k0 = kt * 32 + g * 8;
    float s = s3[row];
    const float* wp = W3 + (size_t)row * D + k0;
    const float* gp = g2 + k0;
    ushort h[8], m_[8], l[8];
#pragma unroll
    for (int j = 0; j < 8; j++) {
        float v = wp[j] * (s * gp[j]);
        split3(v, h[j], m_[j], l[j]);
    }
    size_t dst = tid * 8;
    *(uint4*)(Ph + dst) = pack8(h);
    *(uint4*)(Pm + dst) = pack8(m_);
    *(uint4*)(Pl + dst) = pack8(l);
}

// prepBT: B^T[col][k] = W[k][col], split h/m/l into blocked planes
__global__ __launch_bounds__(256) void prepBT(const float* __restrict__ W,
                                              ushort* __restrict__ Ph,
                                              ushort* __restrict__ Pm,
                                              ushort* __restrict__ Pl) {
    size_t tid = (size_t)blockIdx.x * 256 + threadIdx.x;
    int cell = (int)(tid & 511);
    int kt = (int)((tid >> 9) & 127);
    int bi = (int)(tid >> 16);
    int b = cell >> 6, rg = cell & 63, r = rg >> 2, g = rg & 3;
    int col = bi * 128 + b * 16 + r;
    int k0 = kt * 32 + g * 8;
    ushort h[8], m_[8], l[8];
#pragma unroll
    for (int j = 0; j < 8; j++) {
        float v = W[(size_t)(k0 + j) * D + col];
        split3(v, h[j], m_[j], l[j]);
    }
    size_t dst = tid * 8;
    *(uint4*)(Ph + dst) = pack8(h);
    *(uint4*)(Pm + dst) = pack8(m_);
    *(uint4*)(Pl + dst) = pack8(l);
}

// repackC: row-major split planes -> blocked planes
__global__ __launch_bounds__(256) void repackC(const ushort* __restrict__ Sh,
                                               const ushort* __restrict__ Sm,
                                               const ushort* __restrict__ Sl,
                                               ushort* __restrict__ Dh,
                                               ushort* __restrict__ Dm,
                                               ushort* __restrict__ Dl) {
    size_t tid = (size_t)blockIdx.x * 256 + threadIdx.x;
    int cell = (int)(tid & 511);
    int kt = (int)((tid >> 9) & 127);
    int bi = (int)(tid >> 16);
    int b = cell >> 6, rg = cell & 63, r = rg >> 2, g = rg & 3;
    int row = bi * 128 + b * 16 + r;
    int k0 = kt * 32 + g * 8;
    size_t src = (size_t)row * D + k0;
    size_t dst = tid * 8;
    *(uint4*)(Dh + dst) = *(const uint4*)(Sh + src);
    *(uint4*)(Dm + dst) = *(const uint4*)(Sm + src);
    *(uint4*)(Dl + dst) = *(const uint4*)(Sl + src);
}

// ---- blocked-plane GEMM: O = (Ah+Am+Al)(Bh+Bm+Bl) truncated to 6 products, col-scaled ----
// MODE 0: split O into row-major h/m/l planes. MODE 1: write fp32 O.
template <int MODE>
__global__ __launch_bounds__(256, 2) void gemm_blk(const ushort* __restrict__ Ah,
                                                   const ushort* __restrict__ Am_,
                                                   const ushort* __restrict__ Al_,
                                                   const ushort* __restrict__ Bh,
                                                   const ushort* __restrict__ Bm_,
                                                   const ushort* __restrict__ Bl_,
                                                   const float* __restrict__ cs,
                                                   ushort* __restrict__ Ch,
                                                   ushort* __restrict__ Cm,
                                                   ushort* __restrict__ Cl,
                                                   float* __restrict__ Of) {
    __shared__ ushort lds[6 * 4096];  // 48 KB: Ah Am Al Bh Bm Bl planes, 8KB each
    int t = threadIdx.x;
    int lane = t & 63, wv = t >> 6;
    int wr = wv >> 1, wc = wv & 1;
    int r = lane & 15, g = lane >> 4;
    int bx = blockIdx.x, by = blockIdx.y;

    f32x4 acc[4][4];
#pragma unroll
    for (int m = 0; m < 4; m++)
#pragma unroll
        for (int n = 0; n < 4; n++) acc[m][n] = (f32x4){0.f, 0.f, 0.f, 0.f};

    int afo = wr * 2048 + (r * 4 + g) * 8;  // + m*512 (ushort offset in plane)
    int bfo = wc * 2048 + (r * 4 + g) * 8;  // + n*512

    for (int kt = 0; kt < D / 32; ++kt) {
        size_t at = ((size_t)by * 128 + kt) * 4096;
        size_t bt = ((size_t)bx * 128 + kt) * 4096;
        const ushort* gsrc[6] = {Ah + at, Am_ + at, Al_ + at, Bh + bt, Bm_ + bt, Bl_ + bt};
#pragma unroll
        for (int p = 0; p < 6; p++) {
#pragma unroll
            for (int i = 0; i < 2; i++) {
                int ci = i * 256 + t;
                __builtin_amdgcn_global_load_lds(
                    (const __attribute__((address_space(1))) uint32_t*)(gsrc[p] + ci * 8),
                    (__attribute__((address_space(3))) uint32_t*)(&lds[p * 4096 + ci * 8]),
                    16, 0, 0);
            }
        }
        __syncthreads();  // drains vmcnt(0): staged tile visible to all waves

        bf16x8 bhv[4], bmv[4], blv[4], av[4];
#pragma unroll
        for (int n = 0; n < 4; n++) bhv[n] = *(const bf16x8*)&lds[3 * 4096 + bfo + n * 512];
#pragma unroll
        for (int n = 0; n < 4; n++) bmv[n] = *(const bf16x8*)&lds[4 * 4096 + bfo + n * 512];
#pragma unroll
        for (int n = 0; n < 4; n++) blv[n] = *(const bf16x8*)&lds[5 * 4096 + bfo + n * 512];
#pragma unroll
        for (int m = 0; m < 4; m++) av[m] = *(const bf16x8*)&lds[0 * 4096 + afo + m * 512];
#pragma unroll
        for (int m = 0; m < 4; m++)
#pragma unroll
            for (int n = 0; n < 4; n++) {
                acc[m][n] = __builtin_amdgcn_mfma_f32_16x16x32_bf16(av[m], bhv[n], acc[m][n], 0, 0, 0);
                acc[m][n] = __builtin_amdgcn_mfma_f32_16x16x32_bf16(av[m], bmv[n], acc[m][n], 0, 0, 0);
                acc[m][n] = __builtin_amdgcn_mfma_f32_16x16x32_bf16(av[m], blv[n], acc[m][n], 0, 0, 0);
            }
#pragma unroll
        for (int m = 0; m < 4; m++) av[m] = *(const bf16x8*)&lds[1 * 4096 + afo + m * 512];
#pragma unroll
        for (int m = 0; m < 4; m++)
#pragma unroll
            for (int n = 0; n < 4; n++) {
                acc[m][n] = __builtin_amdgcn_mfma_f32_16x16x32_bf16(av[m], bhv[n], acc[m][n], 0, 0, 0);
                acc[m][n] = __builtin_amdgcn_mfma_f32_16x16x32_bf16(av[m], bmv[n], acc[m][n], 0, 0, 0);
            }
#pragma unroll
        for (int m = 0; m < 4; m++) av[m] = *(const bf16x8*)&lds[2 * 4096 + afo + m * 512];
#pragma unroll
        for (int m = 0; m < 4; m++)
#pragma unroll
            for (int n = 0; n < 4; n++)
                acc[m][n] = __builtin_amdgcn_mfma_f32_16x16x32_bf16(av[m], bhv[n], acc[m][n], 0, 0, 0);
        __syncthreads();  // all fragment reads done before next DMA overwrite
    }

    size_t row0 = (size_t)by * 128, col0 = (size_t)bx * 128;
    float csv[4];
#pragma unroll
    for (int n = 0; n < 4; n++) csv[n] = cs[col0 + wc * 64 + n * 16 + r];
#pragma unroll
    for (int m = 0; m < 4; m++)
#pragma unroll
        for (int n = 0; n < 4; n++)
#pragma unroll
            for (int j = 0; j < 4; j++) {
                size_t grow = row0 + wr * 64 + m * 16 + g * 4 + j;
                size_t gcol = col0 + wc * 64 + n * 16 + r;
                float v = acc[m][n][j] * csv[n];
                if (MODE == 0) {
                    ushort h, mm, ll;
                    split3(v, h, mm, ll);
                    Ch[grow * D + gcol] = h;
                    Cm[grow * D + gcol] = mm;
                    Cl[grow * D + gcol] = ll;
                } else {
                    Of[grow * D + gcol] = v;
                }
            }
}

// ================= fallback (R5-proven) GEMM =================
constexpr int BM = 128, BN = 128, LDK = 40;

template <int SCALED>
__global__ __launch_bounds__(256, 2) void gemm3(const float* __restrict__ A,
                                                const float* __restrict__ B,
                                                const float* __restrict__ rs,
                                                const float* __restrict__ ks,
                                                const float* __restrict__ cs,
                                                float* __restrict__ O) {
    __shared__ ushort Ahs[BM][LDK], Ams[BM][LDK], Als[BM][LDK];
    __shared__ ushort Bhs[BN][LDK], Bms[BN][LDK], Bls[BN][LDK];
    int t = threadIdx.x;
    int lane = t & 63, wv = t >> 6;
    int wr = wv >> 1, wc = wv & 1;
    int r = lane & 15, g = lane >> 4;
    size_t row0 = (size_t)blockIdx.y * BM;
    size_t col0 = (size_t)blockIdx.x * BN;
    int sArow = t >> 1, sAk = (t & 1) * 16, sBcol = t & 127, sBk = (t >> 7) * 16;

    f32x4 acc[4][4];
#pragma unroll
    for (int m = 0; m < 4; m++)
#pragma unroll
        for (int n = 0; n < 4; n++) acc[m][n] = (f32x4){0.f, 0.f, 0.f, 0.f};

    float av[16], bv[16];
    auto LOADT = [&](int k0) {
        const float4* pa = (const float4*)(A + (row0 + sArow) * (size_t)D + k0 + sAk);
#pragma unroll
        for (int q = 0; q < 4; q++) {
            float4 w = pa[q];
            av[q * 4 + 0] = w.x; av[q * 4 + 1] = w.y; av[q * 4 + 2] = w.z; av[q * 4 + 3] = w.w;
        }
        if (SCALED) {
            float rsv = rs[row0 + sArow];
            const float4* pk = (const float4*)(ks + k0 + sAk);
#pragma unroll
            for (int q = 0; q < 4; q++) {
                float4 kk = pk[q];
                av[q * 4 + 0] *= rsv * kk.x; av[q * 4 + 1] *= rsv * kk.y;
                av[q * 4 + 2] *= rsv * kk.z; av[q * 4 + 3] *= rsv * kk.w;
            }
        }
        const float* pb = B + ((size_t)k0 + sBk) * D + col0 + sBcol;
#pragma unroll
        for (int kk = 0; kk < 16; kk++) bv[kk] = pb[(size_t)kk * D];
    };

    LOADT(0);
    for (int kt = 0; kt < D / 32; ++kt) {
        __syncthreads();
        {
            ushort h[16], m_[16], l[16];
#pragma unroll
            for (int j = 0; j < 16; j++) split3(av[j], h[j], m_[j], l[j]);
            *(uint4*)&Ahs[sArow][sAk] = pack8(h);
            *(uint4*)&Ahs[sArow][sAk + 8] = pack8(h + 8);
            *(uint4*)&Ams[sArow][sAk] = pack8(m_);
            *(uint4*)&Ams[sArow][sAk + 8] = pack8(m_ + 8);
            *(uint4*)&Als[sArow][sAk] = pack8(l);
            *(uint4*)&Als[sArow][sAk + 8] = pack8(l + 8);
        }
        {
            ushort h[16], m_[16], l[16];
#pragma unroll
            for (int j = 0; j < 16; j++) split3(bv[j], h[j], m_[j], l[j]);
            *(uint4*)&Bhs[sBcol][sBk] = pack8(h);
            *(uint4*)&Bhs[sBcol][sBk + 8] = pack8(h + 8);
            *(uint4*)&Bms[sBcol][sBk] = pack8(m_);
            *(uint4*)&Bms[sBcol][sBk + 8] = pack8(m_ + 8);
            *(uint4*)&Bls[sBcol][sBk] = pack8(l);
            *(uint4*)&Bls[sBcol][sBk + 8] = pack8(l + 8);
        }
        __syncthreads();
        if (kt + 1 < D / 32) LOADT((kt + 1) * 32);

        bf16x8 bh[4], bm[4], bl[4];
#pragma unroll
        for (int n = 0; n < 4; n++) {
            bh[n] = *(const bf16x8*)&Bhs[wc * 64 + n * 16 + r][g * 8];
            bm[n] = *(const bf16x8*)&Bms[wc * 64 + n * 16 + r][g * 8];
            bl[n] = *(const bf16x8*)&Bls[wc * 64 + n * 16 + r][g * 8];
        }
#pragma unroll
        for (int m = 0; m < 4; m++) {
            bf16x8 ah = *(const bf16x8*)&Ahs[wr * 64 + m * 16 + r][g * 8];
            bf16x8 am = *(const bf16x8*)&Ams[wr * 64 + m * 16 + r][g * 8];
            bf16x8 al = *(const bf16x8*)&Als[wr * 64 + m * 16 + r][g * 8];
#pragma unroll
            for (int n = 0; n < 4; n++) {
                acc[m][n] = __builtin_amdgcn_mfma_f32_16x16x32_bf16(ah, bh[n], acc[m][n], 0, 0, 0);
                acc[m][n] = __builtin_amdgcn_mfma_f32_16x16x32_bf16(ah, bm[n], acc[m][n], 0, 0, 0);
                acc[m][n] = __builtin_amdgcn_mfma_f32_16x16x32_bf16(am, bh[n], acc[m][n], 0, 0, 0);
                acc[m][n] = __builtin_amdgcn_mfma_f32_16x16x32_bf16(am, bm[n], acc[m][n], 0, 0, 0);
                acc[m][n] = __builtin_amdgcn_mfma_f32_16x16x32_bf16(ah, bl[n], acc[m][n], 0, 0, 0);
                acc[m][n] = __builtin_amdgcn_mfma_f32_16x16x32_bf16(al, bh[n], acc[m][n], 0, 0, 0);
            }
        }
    }
    float csv[4];
#pragma unroll
    for (int n = 0; n < 4; n++) csv[n] = cs[col0 + wc * 64 + n * 16 + r];
#pragma unroll
    for (int m = 0; m < 4; m++)
#pragma unroll
        for (int n = 0; n < 4; n++)
#pragma unroll
            for (int j = 0; j < 4; j++) {
                size_t grow = row0 + wr * 64 + m * 16 + g * 4 + j;
                size_t gcol = col0 + wc * 64 + n * 16 + r;
                O[grow * D + gcol] = acc[m][n][j] * csv[n];
            }
}

extern "C" void kernel_launch(void* const* d_in, const int* in_sizes, int n_in,
                              void* d_out, int out_size, void* d_ws, size_t ws_size,
                              hipStream_t stream) {
    const float* x = (const float*)d_in[0];
    const float* W1 = (const float*)d_in[1];
    const float* b1 = (const float*)d_in[2];
    const float* W2 = (const float*)d_in[3];
    const float* b2 = (const float*)d_in[4];
    const float* W3 = (const float*)d_in[5];
    const float* b3 = (const float*)d_in[6];

    float* out = (float*)d_out;
    float* Rout = out + D;

    char* ws = (char*)d_ws;
    float* z1 = (float*)ws;
    float* z2 = z1 + D;
    float* z3 = z2 + D;
    float* a1 = z3 + D;
    float* a2 = a1 + D;
    float* s3 = a2 + D;
    float* g2 = s3 + D;
    float* g1 = g2 + D;
    size_t smallB = (size_t)D * 8 * sizeof(float);

    const size_t PL = (size_t)D * D;  // ushorts per plane (32 MB)
    size_t NEED = smallB + 9 * PL * sizeof(ushort) + 256;

    // forward pass — bit-exact numpy-f32 emulation (unchanged)
    gemv_blas8<<<(D * 8) / 256, 256, 0, stream>>>(W1, x, b1, z1, a1, 1);
    gemv_blas8<<<(D * 8) / 256, 256, 0, stream>>>(W2, a1, b2, z2, a2, 1);
    gemv_blas8<<<(D * 8) / 256, 256, 0, stream>>>(W3, a2, b3, z3, nullptr, 0);
    vecprep32<<<D / 256, 256, 0, stream>>>(z1, z2, z3, a1, a2, b3, out, s3, g2, g1);

    dim3 gg(D / 128, D / 128);
    if (ws_size >= NEED) {
        // fast path: pre-split blocked planes, DMA-staged GEMMs
        ushort* R0 = (ushort*)(ws + smallB);  // A1 planes, later BT1 planes
        ushort* R1 = R0 + 3 * PL;             // BT2 planes, later Cblk planes
        ushort* R2 = R1 + 3 * PL;             // Crm planes (row-major C split)
        int pgrid = (int)((2 * PL / 8) / 256);  // 2M cells / 256
        prepA1<<<pgrid, 256, 0, stream>>>(W3, s3, g2, R0, R0 + PL, R0 + 2 * PL);
        prepBT<<<pgrid, 256, 0, stream>>>(W2, R1, R1 + PL, R1 + 2 * PL);
        gemm_blk<0><<<gg, 256, 0, stream>>>(R0, R0 + PL, R0 + 2 * PL,
                                            R1, R1 + PL, R1 + 2 * PL, g1,
                                            R2, R2 + PL, R2 + 2 * PL, nullptr);
        // A1 dead -> BT1 into R0; BT2 dead -> Cblk into R1
        repackC<<<pgrid, 256, 0, stream>>>(R2, R2 + PL, R2 + 2 * PL,
                                           R1, R1 + PL, R1 + 2 * PL);
        prepBT<<<pgrid, 256, 0, stream>>>(W1, R0, R0 + PL, R0 + 2 * PL);
        gemm_blk<1><<<gg, 256, 0, stream>>>(R1, R1 + PL, R1 + 2 * PL,
                                            R0, R0 + PL, R0 + 2 * PL, x,
                                            nullptr, nullptr, nullptr, Rout);
    } else {
        // fallback: R5-proven in-kernel-split GEMMs (needs only 64 MB + 32 KB)
        float* C = (float*)(ws + smallB);
        gemm3<1><<<gg, 256, 0, stream>>>(W3, W2, s3, g2, g1, C);
        gemm3<0><<<gg, 256, 0, stream>>>(C, W1, nullptr, nullptr, x, Rout);
    }
}

// Round 7
// 1792.694 us; speedup vs baseline: 1.1312x; 1.1312x over previous
//
#include <hip/hip_runtime.h>
#include <stdint.h>

#define D 4096

typedef __attribute__((ext_vector_type(8))) short bf16x8;
typedef __attribute__((ext_vector_type(4))) float f32x4;

__device__ __forceinline__ float bf2f_u(uint hbits_lo16) {
    return __uint_as_float(hbits_lo16 << 16);
}
__device__ __forceinline__ float sgnf(float z) {
    return (z > 0.f) ? 1.f : ((z < 0.f) ? -1.f : 0.f);
}

// HW pair convert+pack: dst = { lo16: bf16(a), hi16: bf16(b) }  (gfx950)
__device__ __forceinline__ uint cvtpk(float a, float b) {
    uint r;
    asm("v_cvt_pk_bf16_f32 %0, %1, %2" : "=v"(r) : "v"(a), "v"(b));
    return r;
}
// triple-split a pair of fp32 into packed h/m/l bf16 pairs.
// Exact-residual construction: works for any faithful rounding of cvt.
__device__ __forceinline__ void split3_pk(float f0, float f1, uint& hp, uint& mp, uint& lp) {
    hp = cvtpk(f0, f1);
    float h0 = __uint_as_float(hp << 16);
    float h1 = __uint_as_float(hp & 0xffff0000u);
    float r0 = f0 - h0, r1 = f1 - h1;
    mp = cvtpk(r0, r1);
    float m0 = __uint_as_float(mp << 16);
    float m1 = __uint_as_float(mp & 0xffff0000u);
    lp = cvtpk(r0 - m0, r1 - m1);
}

// ---- forward GEMV: bit-exact emulation of numpy-f32 (OpenBLAS AVX2 sgemv_t) ----
// DO NOT TOUCH — bit-exactness of z1/z2/z3 vs the reference is load-bearing.
__global__ __launch_bounds__(256) void gemv_blas8(const float* __restrict__ W,
                                                  const float* __restrict__ v,
                                                  const float* __restrict__ bias,
                                                  float* __restrict__ z,
                                                  float* __restrict__ act, int doAct) {
    int gid = blockIdx.x * 256 + threadIdx.x;
    int row = gid >> 3;
    int l = gid & 7;
    const float* wr = W + (size_t)row * D;
    float acc = 0.f;
    for (int k = l; k < D; k += 8) acc = fmaf(wr[k], v[k], acc);
    float b = acc + __shfl_xor(acc, 4);
    float c = b + __shfl_xor(b, 1);
    float s = c + __shfl_xor(c, 2);
    if (l == 0) {
        z[row] = s;
        if (doAct) act[row] = fmaxf(s + bias[row], 0.f);
    }
}

__global__ __launch_bounds__(256) void vecprep32(const float* __restrict__ z1,
                                                 const float* __restrict__ z2,
                                                 const float* __restrict__ z3,
                                                 const float* __restrict__ a1,
                                                 const float* __restrict__ a2,
                                                 const float* __restrict__ b3,
                                                 float* __restrict__ out,
                                                 float* __restrict__ s3,
                                                 float* __restrict__ g2,
                                                 float* __restrict__ g1) {
    int i = blockIdx.x * 256 + threadIdx.x;
    float z3v = z3[i];
    float o = z3v + b3[i];
    out[i] = o;
    s3[i] = o / (z3v + 1e-9f * sgnf(z3v));
    float z2v = z2[i];
    g2[i] = a2[i] / (z2v + 1e-9f * sgnf(z2v));
    float z1v = z1[i];
    g1[i] = a1[i] / (z1v + 1e-9f * sgnf(z1v));
}

// ================= tier path: pre-split B planes (blocked) =================
// Blocked plane: plane[bi][kt][m][g][r][j]; element = B^T[col = bi*128+m*16+r]
// [k = kt*32+g*8+j]. Tile (bi,kt) = 4096 contiguous ushorts (8 KB).
// Fragment read: wave-linear 1 KB -> conflict-free; staging = linear DMA.
__global__ __launch_bounds__(256) void prepBT(const float* __restrict__ W,
                                              ushort* __restrict__ Ph,
                                              ushort* __restrict__ Pm,
                                              ushort* __restrict__ Pl) {
    size_t ci = (size_t)blockIdx.x * 256 + threadIdx.x;
    int r = (int)(ci & 15);
    int g = (int)((ci >> 4) & 3);
    int m = (int)((ci >> 6) & 7);
    int kt = (int)((ci >> 9) & 127);
    int bi = (int)(ci >> 16);
    int col = bi * 128 + m * 16 + r;
    int k0 = kt * 32 + g * 8;
    float v[8];
#pragma unroll
    for (int j = 0; j < 8; j++) v[j] = W[(size_t)(k0 + j) * D + col];
    uint hp[4], mp[4], lp[4];
#pragma unroll
    for (int j = 0; j < 4; j++) split3_pk(v[2 * j], v[2 * j + 1], hp[j], mp[j], lp[j]);
    size_t dst = ci * 8;
    uint4 u;
    u.x = hp[0]; u.y = hp[1]; u.z = hp[2]; u.w = hp[3]; *(uint4*)(Ph + dst) = u;
    u.x = mp[0]; u.y = mp[1]; u.z = mp[2]; u.w = mp[3]; *(uint4*)(Pm + dst) = u;
    u.x = lp[0]; u.y = lp[1]; u.z = lp[2]; u.w = lp[3]; *(uint4*)(Pl + dst) = u;
}

// gemm_bs: O[i,c] = (Σ_k Asc[i,k]·B[k,c]) · cs[c]; A fp32 (split in-kernel, cvt_pk),
// B pre-split blocked planes (DMA-staged). 6 products: hh+hm+mh+mm+hl+lh.
template <int SCALED>
__global__ __launch_bounds__(256, 2) void gemm_bs(const float* __restrict__ A,
                                                  const ushort* __restrict__ Bh,
                                                  const ushort* __restrict__ Bm_,
                                                  const ushort* __restrict__ Bl_,
                                                  const float* __restrict__ rs,
                                                  const float* __restrict__ ks,
                                                  const float* __restrict__ cs,
                                                  float* __restrict__ O) {
    __shared__ ushort ldsA[3][4096];
    __shared__ ushort ldsB[3][4096];
    int t = threadIdx.x;
    int lane = t & 63, wv = t >> 6;
    int wr = wv >> 1, wc = wv & 1;
    int r = lane & 15, g = lane >> 4;
    int bx = blockIdx.x, by = blockIdx.y;
    size_t row0 = (size_t)by * 128, col0 = (size_t)bx * 128;

    int rr = t >> 1;        // staged A row 0..127
    int kh = t & 1;         // k half (16 fp32)
    // blocked LDS cell bases for the two g-cells this thread writes (ushort idx)
    int cellb0 = ((rr >> 4) * 64 + (kh * 2 + 0) * 16 + (rr & 15)) * 8;
    int cellb1 = ((rr >> 4) * 64 + (kh * 2 + 1) * 16 + (rr & 15)) * 8;

    f32x4 acc[4][4];
#pragma unroll
    for (int m = 0; m < 4; m++)
#pragma unroll
        for (int n = 0; n < 4; n++) acc[m][n] = (f32x4){0.f, 0.f, 0.f, 0.f};

    float rsv = SCALED ? rs[row0 + rr] : 0.f;
    const float* arow = A + (row0 + rr) * (size_t)D;

    float av[16];
    auto LOADA = [&](int k0) {
        const float4* pa = (const float4*)(arow + k0 + kh * 16);
#pragma unroll
        for (int q = 0; q < 4; q++) {
            float4 w = pa[q];
            av[q * 4 + 0] = w.x; av[q * 4 + 1] = w.y;
            av[q * 4 + 2] = w.z; av[q * 4 + 3] = w.w;
        }
        if (SCALED) {
            const float4* pk = (const float4*)(ks + k0 + kh * 16);
#pragma unroll
            for (int q = 0; q < 4; q++) {
                float4 kk = pk[q];
                av[q * 4 + 0] *= rsv * kk.x; av[q * 4 + 1] *= rsv * kk.y;
                av[q * 4 + 2] *= rsv * kk.z; av[q * 4 + 3] *= rsv * kk.w;
            }
        }
    };

    LOADA(0);

    for (int kt = 0; kt < D / 32; ++kt) {
        __syncthreads();  // previous tile's fragment reads complete
        // B: direct-to-LDS DMA (issue first so latency hides under A staging)
        size_t bt = ((size_t)bx * 128 + kt) * 4096;
        const ushort* bsrc[3] = {Bh + bt, Bm_ + bt, Bl_ + bt};
#pragma unroll
        for (int p = 0; p < 3; p++) {
            __builtin_amdgcn_global_load_lds(
                (const __attribute__((address_space(1))) uint32_t*)(bsrc[p] + (size_t)t * 8),
                (__attribute__((address_space(3))) uint32_t*)(&ldsB[p][t * 8]), 16, 0, 0);
            __builtin_amdgcn_global_load_lds(
                (const __attribute__((address_space(1))) uint32_t*)(bsrc[p] + (size_t)(t + 256) * 8),
                (__attribute__((address_space(3))) uint32_t*)(&ldsB[p][(t + 256) * 8]), 16, 0, 0);
        }
        // A: split via cvt_pk, write blocked layout
        {
            uint hp[8], mp[8], lp[8];
#pragma unroll
            for (int j = 0; j < 8; j++) split3_pk(av[2 * j], av[2 * j + 1], hp[j], mp[j], lp[j]);
            uint4 u;
            u.x = hp[0]; u.y = hp[1]; u.z = hp[2]; u.w = hp[3]; *(uint4*)&ldsA[0][cellb0] = u;
            u.x = hp[4]; u.y = hp[5]; u.z = hp[6]; u.w = hp[7]; *(uint4*)&ldsA[0][cellb1] = u;
            u.x = mp[0]; u.y = mp[1]; u.z = mp[2]; u.w = mp[3]; *(uint4*)&ldsA[1][cellb0] = u;
            u.x = mp[4]; u.y = mp[5]; u.z = mp[6]; u.w = mp[7]; *(uint4*)&ldsA[1][cellb1] = u;
            u.x = lp[0]; u.y = lp[1]; u.z = lp[2]; u.w = lp[3]; *(uint4*)&ldsA[2][cellb0] = u;
            u.x = lp[4]; u.y = lp[5]; u.z = lp[6]; u.w = lp[7]; *(uint4*)&ldsA[2][cellb1] = u;
        }
        __syncthreads();  // drains vmcnt(0)+lgkmcnt(0): tile fully staged

        if (kt + 1 < D / 32) LOADA((kt + 1) * 32);  // prefetch under MFMA

        bf16x8 bh[4], bm[4], bl[4];
#pragma unroll
        for (int n = 0; n < 4; n++) bh[n] = *(const bf16x8*)&ldsB[0][(wc * 4 + n) * 512 + lane * 8];
#pragma unroll
        for (int n = 0; n < 4; n++) bm[n] = *(const bf16x8*)&ldsB[1][(wc * 4 + n) * 512 + lane * 8];
#pragma unroll
        for (int n = 0; n < 4; n++) bl[n] = *(const bf16x8*)&ldsB[2][(wc * 4 + n) * 512 + lane * 8];
        {
            bf16x8 a[4];
#pragma unroll
            for (int m = 0; m < 4; m++) a[m] = *(const bf16x8*)&ldsA[0][(wr * 4 + m) * 512 + lane * 8];
#pragma unroll
            for (int m = 0; m < 4; m++)
#pragma unroll
                for (int n = 0; n < 4; n++) {
                    acc[m][n] = __builtin_amdgcn_mfma_f32_16x16x32_bf16(a[m], bh[n], acc[m][n], 0, 0, 0);
                    acc[m][n] = __builtin_amdgcn_mfma_f32_16x16x32_bf16(a[m], bm[n], acc[m][n], 0, 0, 0);
                    acc[m][n] = __builtin_amdgcn_mfma_f32_16x16x32_bf16(a[m], bl[n], acc[m][n], 0, 0, 0);
                }
        }
        {
            bf16x8 a[4];
#pragma unroll
            for (int m = 0; m < 4; m++) a[m] = *(const bf16x8*)&ldsA[1][(wr * 4 + m) * 512 + lane * 8];
#pragma unroll
            for (int m = 0; m < 4; m++)
#pragma unroll
                for (int n = 0; n < 4; n++) {
                    acc[m][n] = __builtin_amdgcn_mfma_f32_16x16x32_bf16(a[m], bh[n], acc[m][n], 0, 0, 0);
                    acc[m][n] = __builtin_amdgcn_mfma_f32_16x16x32_bf16(a[m], bm[n], acc[m][n], 0, 0, 0);
                }
        }
        {
            bf16x8 a[4];
#pragma unroll
            for (int m = 0; m < 4; m++) a[m] = *(const bf16x8*)&ldsA[2][(wr * 4 + m) * 512 + lane * 8];
#pragma unroll
            for (int m = 0; m < 4; m++)
#pragma unroll
                for (int n = 0; n < 4; n++)
                    acc[m][n] = __builtin_amdgcn_mfma_f32_16x16x32_bf16(a[m], bh[n], acc[m][n], 0, 0, 0);
        }
    }

    float csv[4];
#pragma unroll
    for (int n = 0; n < 4; n++) csv[n] = cs[col0 + wc * 64 + n * 16 + r];
#pragma unroll
    for (int m = 0; m < 4; m++)
#pragma unroll
        for (int n = 0; n < 4; n++)
#pragma unroll
            for (int j = 0; j < 4; j++) {
                size_t grow = row0 + wr * 64 + m * 16 + g * 4 + j;
                size_t gcol = col0 + wc * 64 + n * 16 + r;
                O[grow * D + gcol] = acc[m][n][j] * csv[n];
            }
}

// ================= fallback (R5-proven structure, cvt_pk splits) =================
constexpr int BM = 128, BN = 128, LDK = 40;

template <int SCALED>
__global__ __launch_bounds__(256, 2) void gemm3(const float* __restrict__ A,
                                                const float* __restrict__ B,
                                                const float* __restrict__ rs,
                                                const float* __restrict__ ks,
                                                const float* __restrict__ cs,
                                                float* __restrict__ O) {
    __shared__ ushort Ahs[BM][LDK], Ams[BM][LDK], Als[BM][LDK];
    __shared__ ushort Bhs[BN][LDK], Bms[BN][LDK], Bls[BN][LDK];
    int t = threadIdx.x;
    int lane = t & 63, wv = t >> 6;
    int wr = wv >> 1, wc = wv & 1;
    int r = lane & 15, g = lane >> 4;
    size_t row0 = (size_t)blockIdx.y * BM;
    size_t col0 = (size_t)blockIdx.x * BN;
    int sArow = t >> 1, sAk = (t & 1) * 16, sBcol = t & 127, sBk = (t >> 7) * 16;

    f32x4 acc[4][4];
#pragma unroll
    for (int m = 0; m < 4; m++)
#pragma unroll
        for (int n = 0; n < 4; n++) acc[m][n] = (f32x4){0.f, 0.f, 0.f, 0.f};

    float av[16], bv[16];
    auto LOADT = [&](int k0) {
        const float4* pa = (const float4*)(A + (row0 + sArow) * (size_t)D + k0 + sAk);
#pragma unroll
        for (int q = 0; q < 4; q++) {
            float4 w = pa[q];
            av[q * 4 + 0] = w.x; av[q * 4 + 1] = w.y; av[q * 4 + 2] = w.z; av[q * 4 + 3] = w.w;
        }
        if (SCALED) {
            float rsv = rs[row0 + sArow];
            const float4* pk = (const float4*)(ks + k0 + sAk);
#pragma unroll
            for (int q = 0; q < 4; q++) {
                float4 kk = pk[q];
                av[q * 4 + 0] *= rsv * kk.x; av[q * 4 + 1] *= rsv * kk.y;
                av[q * 4 + 2] *= rsv * kk.z; av[q * 4 + 3] *= rsv * kk.w;
            }
        }
        const float* pb = B + ((size_t)k0 + sBk) * D + col0 + sBcol;
#pragma unroll
        for (int kk = 0; kk < 16; kk++) bv[kk] = pb[(size_t)kk * D];
    };

    LOADT(0);
    for (int kt = 0; kt < D / 32; ++kt) {
        __syncthreads();
        {
            uint hp[8], mp[8], lp[8];
#pragma unroll
            for (int j = 0; j < 8; j++) split3_pk(av[2 * j], av[2 * j + 1], hp[j], mp[j], lp[j]);
            uint4 u;
            u.x = hp[0]; u.y = hp[1]; u.z = hp[2]; u.w = hp[3]; *(uint4*)&Ahs[sArow][sAk] = u;
            u.x = hp[4]; u.y = hp[5]; u.z = hp[6]; u.w = hp[7]; *(uint4*)&Ahs[sArow][sAk + 8] = u;
            u.x = mp[0]; u.y = mp[1]; u.z = mp[2]; u.w = mp[3]; *(uint4*)&Ams[sArow][sAk] = u;
            u.x = mp[4]; u.y = mp[5]; u.z = mp[6]; u.w = mp[7]; *(uint4*)&Ams[sArow][sAk + 8] = u;
            u.x = lp[0]; u.y = lp[1]; u.z = lp[2]; u.w = lp[3]; *(uint4*)&Als[sArow][sAk] = u;
            u.x = lp[4]; u.y = lp[5]; u.z = lp[6]; u.w = lp[7]; *(uint4*)&Als[sArow][sAk + 8] = u;
        }
        {
            uint hp[8], mp[8], lp[8];
#pragma unroll
            for (int j = 0; j < 8; j++) split3_pk(bv[2 * j], bv[2 * j + 1], hp[j], mp[j], lp[j]);
            uint4 u;
            u.x = hp[0]; u.y = hp[1]; u.z = hp[2]; u.w = hp[3]; *(uint4*)&Bhs[sBcol][sBk] = u;
            u.x = hp[4]; u.y = hp[5]; u.z = hp[6]; u.w = hp[7]; *(uint4*)&Bhs[sBcol][sBk + 8] = u;
            u.x = mp[0]; u.y = mp[1]; u.z = mp[2]; u.w = mp[3]; *(uint4*)&Bms[sBcol][sBk] = u;
            u.x = mp[4]; u.y = mp[5]; u.z = mp[6]; u.w = mp[7]; *(uint4*)&Bms[sBcol][sBk + 8] = u;
            u.x = lp[0]; u.y = lp[1]; u.z = lp[2]; u.w = lp[3]; *(uint4*)&Bls[sBcol][sBk] = u;
            u.x = lp[4]; u.y = lp[5]; u.z = lp[6]; u.w = lp[7]; *(uint4*)&Bls[sBcol][sBk + 8] = u;
        }
        __syncthreads();
        if (kt + 1 < D / 32) LOADT((kt + 1) * 32);

        bf16x8 bh[4], bm[4], bl[4];
#pragma unroll
        for (int n = 0; n < 4; n++) {
            bh[n] = *(const bf16x8*)&Bhs[wc * 64 + n * 16 + r][g * 8];
            bm[n] = *(const bf16x8*)&Bms[wc * 64 + n * 16 + r][g * 8];
            bl[n] = *(const bf16x8*)&Bls[wc * 64 + n * 16 + r][g * 8];
        }
#pragma unroll
        for (int m = 0; m < 4; m++) {
            bf16x8 ah = *(const bf16x8*)&Ahs[wr * 64 + m * 16 + r][g * 8];
            bf16x8 am = *(const bf16x8*)&Ams[wr * 64 + m * 16 + r][g * 8];
            bf16x8 al = *(const bf16x8*)&Als[wr * 64 + m * 16 + r][g * 8];
#pragma unroll
            for (int n = 0; n < 4; n++) {
                acc[m][n] = __builtin_amdgcn_mfma_f32_16x16x32_bf16(ah, bh[n], acc[m][n], 0, 0, 0);
                acc[m][n] = __builtin_amdgcn_mfma_f32_16x16x32_bf16(ah, bm[n], acc[m][n], 0, 0, 0);
                acc[m][n] = __builtin_amdgcn_mfma_f32_16x16x32_bf16(am, bh[n], acc[m][n], 0, 0, 0);
                acc[m][n] = __builtin_amdgcn_mfma_f32_16x16x32_bf16(am, bm[n], acc[m][n], 0, 0, 0);
                acc[m][n] = __builtin_amdgcn_mfma_f32_16x16x32_bf16(ah, bl[n], acc[m][n], 0, 0, 0);
                acc[m][n] = __builtin_amdgcn_mfma_f32_16x16x32_bf16(al, bh[n], acc[m][n], 0, 0, 0);
            }
        }
    }
    float csv[4];
#pragma unroll
    for (int n = 0; n < 4; n++) csv[n] = cs[col0 + wc * 64 + n * 16 + r];
#pragma unroll
    for (int m = 0; m < 4; m++)
#pragma unroll
        for (int n = 0; n < 4; n++)
#pragma unroll
            for (int j = 0; j < 4; j++) {
                size_t grow = row0 + wr * 64 + m * 16 + g * 4 + j;
                size_t gcol = col0 + wc * 64 + n * 16 + r;
                O[grow * D + gcol] = acc[m][n][j] * csv[n];
            }
}

extern "C" void kernel_launch(void* const* d_in, const int* in_sizes, int n_in,
                              void* d_out, int out_size, void* d_ws, size_t ws_size,
                              hipStream_t stream) {
    const float* x = (const float*)d_in[0];
    const float* W1 = (const float*)d_in[1];
    const float* b1 = (const float*)d_in[2];
    const float* W2 = (const float*)d_in[3];
    const float* b2 = (const float*)d_in[4];
    const float* W3 = (const float*)d_in[5];
    const float* b3 = (const float*)d_in[6];

    float* out = (float*)d_out;
    float* Rout = out + D;

    char* ws = (char*)d_ws;
    float* z1 = (float*)ws;
    float* z2 = z1 + D;
    float* z3 = z2 + D;
    float* a1 = z3 + D;
    float* a2 = a1 + D;
    float* s3 = a2 + D;
    float* g2 = s3 + D;
    float* g1 = g2 + D;
    size_t smallB = (size_t)D * 8 * sizeof(float);

    const size_t PL = (size_t)D * D;                       // ushorts per plane
    size_t planesB = 3 * PL * sizeof(ushort);              // 96 MB
    size_t cB = (size_t)D * D * sizeof(float);             // 64 MB
    size_t tierNeed = smallB + planesB + cB + 256;         // ~160.1 MB

    // forward pass — bit-exact numpy-f32 emulation (unchanged)
    gemv_blas8<<<(D * 8) / 256, 256, 0, stream>>>(W1, x, b1, z1, a1, 1);
    gemv_blas8<<<(D * 8) / 256, 256, 0, stream>>>(W2, a1, b2, z2, a2, 1);
    gemv_blas8<<<(D * 8) / 256, 256, 0, stream>>>(W3, a2, b3, z3, nullptr, 0);
    vecprep32<<<D / 256, 256, 0, stream>>>(z1, z2, z3, a1, a2, b3, out, s3, g2, g1);

    dim3 gg(D / 128, D / 128);
    if (ws_size >= tierNeed) {
        ushort* Bpl = (ushort*)(ws + smallB);
        float* C = (float*)(ws + smallB + planesB);
        int pgrid = (int)((PL / 8) / 256);  // 8192 blocks
        prepBT<<<pgrid, 256, 0, stream>>>(W2, Bpl, Bpl + PL, Bpl + 2 * PL);
        gemm_bs<1><<<gg, 256, 0, stream>>>(W3, Bpl, Bpl + PL, Bpl + 2 * PL, s3, g2, g1, C);
        prepBT<<<pgrid, 256, 0, stream>>>(W1, Bpl, Bpl + PL, Bpl + 2 * PL);
        gemm_bs<0><<<gg, 256, 0, stream>>>(C, Bpl, Bpl + PL, Bpl + 2 * PL, nullptr, nullptr, x, Rout);
    } else {
        float* C = (float*)(ws + smallB);
        gemm3<1><<<gg, 256, 0, stream>>>(W3, W2, s3, g2, g1, C);
        gemm3<0><<<gg, 256, 0, stream>>>(C, W1, nullptr, nullptr, x, Rout);
    }
}

// Round 8
// 1613.782 us; speedup vs baseline: 1.2566x; 1.1109x over previous
//
#include <hip/hip_runtime.h>
#include <stdint.h>

#define D 4096

typedef __attribute__((ext_vector_type(8))) short bf16x8;
typedef __attribute__((ext_vector_type(4))) float f32x4;

__device__ __forceinline__ float sgnf(float z) {
    return (z > 0.f) ? 1.f : ((z < 0.f) ? -1.f : 0.f);
}

// HW pair convert+pack: dst = { lo16: bf16(a), hi16: bf16(b) }  (gfx950)
__device__ __forceinline__ uint cvtpk(float a, float b) {
    uint r;
    asm("v_cvt_pk_bf16_f32 %0, %1, %2" : "=v"(r) : "v"(a), "v"(b));
    return r;
}
// triple-split a pair of fp32 into packed h/m/l bf16 pairs (exact residuals).
__device__ __forceinline__ void split3_pk(float f0, float f1, uint& hp, uint& mp, uint& lp) {
    hp = cvtpk(f0, f1);
    float h0 = __uint_as_float(hp << 16);
    float h1 = __uint_as_float(hp & 0xffff0000u);
    float r0 = f0 - h0, r1 = f1 - h1;
    mp = cvtpk(r0, r1);
    float m0 = __uint_as_float(mp << 16);
    float m1 = __uint_as_float(mp & 0xffff0000u);
    lp = cvtpk(r0 - m0, r1 - m1);
}

// ---- forward GEMV: bit-exact emulation of numpy-f32 (OpenBLAS AVX2 sgemv_t) ----
// DO NOT TOUCH — bit-exactness of z1/z2/z3 vs the reference is load-bearing.
__global__ __launch_bounds__(256) void gemv_blas8(const float* __restrict__ W,
                                                  const float* __restrict__ v,
                                                  const float* __restrict__ bias,
                                                  float* __restrict__ z,
                                                  float* __restrict__ act, int doAct) {
    int gid = blockIdx.x * 256 + threadIdx.x;
    int row = gid >> 3;
    int l = gid & 7;
    const float* wr = W + (size_t)row * D;
    float acc = 0.f;
    for (int k = l; k < D; k += 8) acc = fmaf(wr[k], v[k], acc);
    float b = acc + __shfl_xor(acc, 4);
    float c = b + __shfl_xor(b, 1);
    float s = c + __shfl_xor(c, 2);
    if (l == 0) {
        z[row] = s;
        if (doAct) act[row] = fmaxf(s + bias[row], 0.f);
    }
}

__global__ __launch_bounds__(256) void vecprep32(const float* __restrict__ z1,
                                                 const float* __restrict__ z2,
                                                 const float* __restrict__ z3,
                                                 const float* __restrict__ a1,
                                                 const float* __restrict__ a2,
                                                 const float* __restrict__ b3,
                                                 float* __restrict__ out,
                                                 float* __restrict__ s3,
                                                 float* __restrict__ g2,
                                                 float* __restrict__ g1) {
    int i = blockIdx.x * 256 + threadIdx.x;
    float z3v = z3[i];
    float o = z3v + b3[i];
    out[i] = o;
    s3[i] = o / (z3v + 1e-9f * sgnf(z3v));
    float z2v = z2[i];
    g2[i] = a2[i] / (z2v + 1e-9f * sgnf(z2v));
    float z1v = z1[i];
    g1[i] = a1[i] / (z1v + 1e-9f * sgnf(z1v));
}

// ================= tier path: pre-split B planes (blocked) =================
// Blocked plane: plane[bi][kt][m][g][r][j]; element = B^T[col = bi*128+m*16+r]
// [k = kt*32+g*8+j]. Tile (bi,kt) = 4096 contiguous ushorts (8 KB).
__global__ __launch_bounds__(256) void prepBT(const float* __restrict__ W,
                                              ushort* __restrict__ Ph,
                                              ushort* __restrict__ Pm,
                                              ushort* __restrict__ Pl) {
    size_t ci = (size_t)blockIdx.x * 256 + threadIdx.x;
    int r = (int)(ci & 15);
    int g = (int)((ci >> 4) & 3);
    int m = (int)((ci >> 6) & 7);
    int kt = (int)((ci >> 9) & 127);
    int bi = (int)(ci >> 16);
    int col = bi * 128 + m * 16 + r;
    int k0 = kt * 32 + g * 8;
    float v[8];
#pragma unroll
    for (int j = 0; j < 8; j++) v[j] = W[(size_t)(k0 + j) * D + col];
    uint hp[4], mp[4], lp[4];
#pragma unroll
    for (int j = 0; j < 4; j++) split3_pk(v[2 * j], v[2 * j + 1], hp[j], mp[j], lp[j]);
    size_t dst = ci * 8;
    uint4 u;
    u.x = hp[0]; u.y = hp[1]; u.z = hp[2]; u.w = hp[3]; *(uint4*)(Ph + dst) = u;
    u.x = mp[0]; u.y = mp[1]; u.z = mp[2]; u.w = mp[3]; *(uint4*)(Pm + dst) = u;
    u.x = lp[0]; u.y = lp[1]; u.z = lp[2]; u.w = lp[3]; *(uint4*)(Pl + dst) = u;
}

// gemm_bs: O[i,c] = (Σ_k Asc[i,k]·B[k,c]) · cs[c]; A fp32 split in-kernel (cvt_pk),
// B pre-split blocked planes, DMA-staged, DOUBLE-BUFFERED with counted vmcnt.
// 6 products: hh+hm+mh+mm+hl+lh.
template <int SCALED>
__global__ __launch_bounds__(256, 2) void gemm_bs(const float* __restrict__ A,
                                                  const ushort* __restrict__ Bh,
                                                  const ushort* __restrict__ Bm_,
                                                  const ushort* __restrict__ Bl_,
                                                  const float* __restrict__ rs,
                                                  const float* __restrict__ ks,
                                                  const float* __restrict__ cs,
                                                  float* __restrict__ O) {
    __shared__ ushort ldsA[3][4096];
    __shared__ ushort ldsB[2][3][4096];
    int t = threadIdx.x;
    int lane = t & 63, wv = t >> 6;
    int wr = wv >> 1, wc = wv & 1;
    int r = lane & 15, g = lane >> 4;
    int bx = blockIdx.x, by = blockIdx.y;
    size_t row0 = (size_t)by * 128, col0 = (size_t)bx * 128;

    int rr = t >> 1;  // staged A row 0..127
    int kh = t & 1;   // k half (16 fp32)
    int cellb0 = ((rr >> 4) * 64 + (kh * 2 + 0) * 16 + (rr & 15)) * 8;
    int cellb1 = ((rr >> 4) * 64 + (kh * 2 + 1) * 16 + (rr & 15)) * 8;

    f32x4 acc[4][4];
#pragma unroll
    for (int m = 0; m < 4; m++)
#pragma unroll
        for (int n = 0; n < 4; n++) acc[m][n] = (f32x4){0.f, 0.f, 0.f, 0.f};

    float rsv = SCALED ? rs[row0 + rr] : 0.f;
    const float* arow = A + (row0 + rr) * (size_t)D;

    float av[16];
    auto LOADA = [&](int k0) {
        const float4* pa = (const float4*)(arow + k0 + kh * 16);
#pragma unroll
        for (int q = 0; q < 4; q++) {
            float4 w = pa[q];
            av[q * 4 + 0] = w.x; av[q * 4 + 1] = w.y;
            av[q * 4 + 2] = w.z; av[q * 4 + 3] = w.w;
        }
        if (SCALED) {
            const float4* pk = (const float4*)(ks + k0 + kh * 16);
#pragma unroll
            for (int q = 0; q < 4; q++) {
                float4 kk = pk[q];
                av[q * 4 + 0] *= rsv * kk.x; av[q * 4 + 1] *= rsv * kk.y;
                av[q * 4 + 2] *= rsv * kk.z; av[q * 4 + 3] *= rsv * kk.w;
            }
        }
    };

    auto DMAB = [&](int kt, int buf) {
        size_t bt = ((size_t)bx * 128 + kt) * 4096;
        const ushort* bsrc[3] = {Bh + bt, Bm_ + bt, Bl_ + bt};
#pragma unroll
        for (int p = 0; p < 3; p++) {
            __builtin_amdgcn_global_load_lds(
                (const __attribute__((address_space(1))) uint32_t*)(bsrc[p] + (size_t)t * 8),
                (__attribute__((address_space(3))) uint32_t*)(&ldsB[buf][p][t * 8]), 16, 0, 0);
            __builtin_amdgcn_global_load_lds(
                (const __attribute__((address_space(1))) uint32_t*)(bsrc[p] + (size_t)(t + 256) * 8),
                (__attribute__((address_space(3))) uint32_t*)(&ldsB[buf][p][(t + 256) * 8]), 16, 0, 0);
        }
    };

    auto SPLITA = [&]() {
        uint hp[8], mp[8], lp[8];
#pragma unroll
        for (int j = 0; j < 8; j++) split3_pk(av[2 * j], av[2 * j + 1], hp[j], mp[j], lp[j]);
        uint4 u;
        u.x = hp[0]; u.y = hp[1]; u.z = hp[2]; u.w = hp[3]; *(uint4*)&ldsA[0][cellb0] = u;
        u.x = hp[4]; u.y = hp[5]; u.z = hp[6]; u.w = hp[7]; *(uint4*)&ldsA[0][cellb1] = u;
        u.x = mp[0]; u.y = mp[1]; u.z = mp[2]; u.w = mp[3]; *(uint4*)&ldsA[1][cellb0] = u;
        u.x = mp[4]; u.y = mp[5]; u.z = mp[6]; u.w = mp[7]; *(uint4*)&ldsA[1][cellb1] = u;
        u.x = lp[0]; u.y = lp[1]; u.z = lp[2]; u.w = lp[3]; *(uint4*)&ldsA[2][cellb0] = u;
        u.x = lp[4]; u.y = lp[5]; u.z = lp[6]; u.w = lp[7]; *(uint4*)&ldsA[2][cellb1] = u;
    };

    auto MFMA_PHASE = [&](int buf) {
        bf16x8 bh[4], bm[4], bl[4];
#pragma unroll
        for (int n = 0; n < 4; n++) bh[n] = *(const bf16x8*)&ldsB[buf][0][(wc * 4 + n) * 512 + lane * 8];
#pragma unroll
        for (int n = 0; n < 4; n++) bm[n] = *(const bf16x8*)&ldsB[buf][1][(wc * 4 + n) * 512 + lane * 8];
#pragma unroll
        for (int n = 0; n < 4; n++) bl[n] = *(const bf16x8*)&ldsB[buf][2][(wc * 4 + n) * 512 + lane * 8];
        {
            bf16x8 a[4];
#pragma unroll
            for (int m = 0; m < 4; m++) a[m] = *(const bf16x8*)&ldsA[0][(wr * 4 + m) * 512 + lane * 8];
#pragma unroll
            for (int m = 0; m < 4; m++)
#pragma unroll
                for (int n = 0; n < 4; n++) {
                    acc[m][n] = __builtin_amdgcn_mfma_f32_16x16x32_bf16(a[m], bh[n], acc[m][n], 0, 0, 0);
                    acc[m][n] = __builtin_amdgcn_mfma_f32_16x16x32_bf16(a[m], bm[n], acc[m][n], 0, 0, 0);
                    acc[m][n] = __builtin_amdgcn_mfma_f32_16x16x32_bf16(a[m], bl[n], acc[m][n], 0, 0, 0);
                }
        }
        {
            bf16x8 a[4];
#pragma unroll
            for (int m = 0; m < 4; m++) a[m] = *(const bf16x8*)&ldsA[1][(wr * 4 + m) * 512 + lane * 8];
#pragma unroll
            for (int m = 0; m < 4; m++)
#pragma unroll
                for (int n = 0; n < 4; n++) {
                    acc[m][n] = __builtin_amdgcn_mfma_f32_16x16x32_bf16(a[m], bh[n], acc[m][n], 0, 0, 0);
                    acc[m][n] = __builtin_amdgcn_mfma_f32_16x16x32_bf16(a[m], bm[n], acc[m][n], 0, 0, 0);
                }
        }
        {
            bf16x8 a[4];
#pragma unroll
            for (int m = 0; m < 4; m++) a[m] = *(const bf16x8*)&ldsA[2][(wr * 4 + m) * 512 + lane * 8];
#pragma unroll
            for (int m = 0; m < 4; m++)
#pragma unroll
                for (int n = 0; n < 4; n++)
                    acc[m][n] = __builtin_amdgcn_mfma_f32_16x16x32_bf16(a[m], bh[n], acc[m][n], 0, 0, 0);
        }
    };

    const int NT = D / 32;  // 128

    // ---- prologue ----
    LOADA(0);
    SPLITA();        // tile 0 -> ldsA (compiler waits its own av loads)
    DMAB(0, 0);      // 6 DMAs, tile 0
    LOADA(32);       // av <- tile 1 raw
    DMAB(1, 1);      // 6 DMAs, tile 1 (stay in flight)
    asm volatile("s_waitcnt vmcnt(6) lgkmcnt(0)" ::: "memory");  // tile-0 DMAs done
    __builtin_amdgcn_s_barrier();
    __builtin_amdgcn_sched_barrier(0);

    for (int tt = 0; tt < NT; ++tt) {
        MFMA_PHASE(tt & 1);
        __builtin_amdgcn_s_barrier();  // all reads of ldsA / ldsB[tt&1] done
        __builtin_amdgcn_sched_barrier(0);
        if (tt < NT - 1) {
            SPLITA();  // av holds tile tt+1 (its loads drained by last vmcnt)
            if (tt < NT - 2) {
                LOADA((tt + 2) * 32);   // av <- tile tt+2 raw (older than DMAs below)
                DMAB(tt + 2, tt & 1);   // newest 6 vmem ops
                asm volatile("s_waitcnt vmcnt(6) lgkmcnt(0)" ::: "memory");  // tile tt+1 DMAs done
            } else {
                asm volatile("s_waitcnt vmcnt(0) lgkmcnt(0)" ::: "memory");  // last tile: drain
            }
            __builtin_amdgcn_s_barrier();
            __builtin_amdgcn_sched_barrier(0);
        }
    }

    float csv[4];
#pragma unroll
    for (int n = 0; n < 4; n++) csv[n] = cs[col0 + wc * 64 + n * 16 + r];
#pragma unroll
    for (int m = 0; m < 4; m++)
#pragma unroll
        for (int n = 0; n < 4; n++)
#pragma unroll
            for (int j = 0; j < 4; j++) {
                size_t grow = row0 + wr * 64 + m * 16 + g * 4 + j;
                size_t gcol = col0 + wc * 64 + n * 16 + r;
                O[grow * D + gcol] = acc[m][n][j] * csv[n];
            }
}

// ================= fallback (R5-proven structure, cvt_pk splits) =================
constexpr int BM = 128, BN = 128, LDK = 40;

template <int SCALED>
__global__ __launch_bounds__(256, 2) void gemm3(const float* __restrict__ A,
                                                const float* __restrict__ B,
                                                const float* __restrict__ rs,
                                                const float* __restrict__ ks,
                                                const float* __restrict__ cs,
                                                float* __restrict__ O) {
    __shared__ ushort Ahs[BM][LDK], Ams[BM][LDK], Als[BM][LDK];
    __shared__ ushort Bhs[BN][LDK], Bms[BN][LDK], Bls[BN][LDK];
    int t = threadIdx.x;
    int lane = t & 63, wv = t >> 6;
    int wr = wv >> 1, wc = wv & 1;
    int r = lane & 15, g = lane >> 4;
    size_t row0 = (size_t)blockIdx.y * BM;
    size_t col0 = (size_t)blockIdx.x * BN;
    int sArow = t >> 1, sAk = (t & 1) * 16, sBcol = t & 127, sBk = (t >> 7) * 16;

    f32x4 acc[4][4];
#pragma unroll
    for (int m = 0; m < 4; m++)
#pragma unroll
        for (int n = 0; n < 4; n++) acc[m][n] = (f32x4){0.f, 0.f, 0.f, 0.f};

    float av[16], bv[16];
    auto LOADT = [&](int k0) {
        const float4* pa = (const float4*)(A + (row0 + sArow) * (size_t)D + k0 + sAk);
#pragma unroll
        for (int q = 0; q < 4; q++) {
            float4 w = pa[q];
            av[q * 4 + 0] = w.x; av[q * 4 + 1] = w.y; av[q * 4 + 2] = w.z; av[q * 4 + 3] = w.w;
        }
        if (SCALED) {
            float rsv = rs[row0 + sArow];
            const float4* pk = (const float4*)(ks + k0 + sAk);
#pragma unroll
            for (int q = 0; q < 4; q++) {
                float4 kk = pk[q];
                av[q * 4 + 0] *= rsv * kk.x; av[q * 4 + 1] *= rsv * kk.y;
                av[q * 4 + 2] *= rsv * kk.z; av[q * 4 + 3] *= rsv * kk.w;
            }
        }
        const float* pb = B + ((size_t)k0 + sBk) * D + col0 + sBcol;
#pragma unroll
        for (int kk = 0; kk < 16; kk++) bv[kk] = pb[(size_t)kk * D];
    };

    LOADT(0);
    for (int kt = 0; kt < D / 32; ++kt) {
        __syncthreads();
        {
            uint hp[8], mp[8], lp[8];
#pragma unroll
            for (int j = 0; j < 8; j++) split3_pk(av[2 * j], av[2 * j + 1], hp[j], mp[j], lp[j]);
            uint4 u;
            u.x = hp[0]; u.y = hp[1]; u.z = hp[2]; u.w = hp[3]; *(uint4*)&Ahs[sArow][sAk] = u;
            u.x = hp[4]; u.y = hp[5]; u.z = hp[6]; u.w = hp[7]; *(uint4*)&Ahs[sArow][sAk + 8] = u;
            u.x = mp[0]; u.y = mp[1]; u.z = mp[2]; u.w = mp[3]; *(uint4*)&Ams[sArow][sAk] = u;
            u.x = mp[4]; u.y = mp[5]; u.z = mp[6]; u.w = mp[7]; *(uint4*)&Ams[sArow][sAk + 8] = u;
            u.x = lp[0]; u.y = lp[1]; u.z = lp[2]; u.w = lp[3]; *(uint4*)&Als[sArow][sAk] = u;
            u.x = lp[4]; u.y = lp[5]; u.z = lp[6]; u.w = lp[7]; *(uint4*)&Als[sArow][sAk + 8] = u;
        }
        {
            uint hp[8], mp[8], lp[8];
#pragma unroll
            for (int j = 0; j < 8; j++) split3_pk(bv[2 * j], bv[2 * j + 1], hp[j], mp[j], lp[j]);
            uint4 u;
            u.x = hp[0]; u.y = hp[1]; u.z = hp[2]; u.w = hp[3]; *(uint4*)&Bhs[sBcol][sBk] = u;
            u.x = hp[4]; u.y = hp[5]; u.z = hp[6]; u.w = hp[7]; *(uint4*)&Bhs[sBcol][sBk + 8] = u;
            u.x = mp[0]; u.y = mp[1]; u.z = mp[2]; u.w = mp[3]; *(uint4*)&Bms[sBcol][sBk] = u;
            u.x = mp[4]; u.y = mp[5]; u.z = mp[6]; u.w = mp[7]; *(uint4*)&Bms[sBcol][sBk + 8] = u;
            u.x = lp[0]; u.y = lp[1]; u.z = lp[2]; u.w = lp[3]; *(uint4*)&Bls[sBcol][sBk] = u;
            u.x = lp[4]; u.y = lp[5]; u.z = lp[6]; u.w = lp[7]; *(uint4*)&Bls[sBcol][sBk + 8] = u;
        }
        __syncthreads();
        if (kt + 1 < D / 32) LOADT((kt + 1) * 32);

        bf16x8 bh[4], bm[4], bl[4];
#pragma unroll
        for (int n = 0; n < 4; n++) {
            bh[n] = *(const bf16x8*)&Bhs[wc * 64 + n * 16 + r][g * 8];
            bm[n] = *(const bf16x8*)&Bms[wc * 64 + n * 16 + r][g * 8];
            bl[n] = *(const bf16x8*)&Bls[wc * 64 + n * 16 + r][g * 8];
        }
#pragma unroll
        for (int m = 0; m < 4; m++) {
            bf16x8 ah = *(const bf16x8*)&Ahs[wr * 64 + m * 16 + r][g * 8];
            bf16x8 am = *(const bf16x8*)&Ams[wr * 64 + m * 16 + r][g * 8];
            bf16x8 al = *(const bf16x8*)&Als[wr * 64 + m * 16 + r][g * 8];
#pragma unroll
            for (int n = 0; n < 4; n++) {
                acc[m][n] = __builtin_amdgcn_mfma_f32_16x16x32_bf16(ah, bh[n], acc[m][n], 0, 0, 0);
                acc[m][n] = __builtin_amdgcn_mfma_f32_16x16x32_bf16(ah, bm[n], acc[m][n], 0, 0, 0);
                acc[m][n] = __builtin_amdgcn_mfma_f32_16x16x32_bf16(am, bh[n], acc[m][n], 0, 0, 0);
                acc[m][n] = __builtin_amdgcn_mfma_f32_16x16x32_bf16(am, bm[n], acc[m][n], 0, 0, 0);
                acc[m][n] = __builtin_amdgcn_mfma_f32_16x16x32_bf16(ah, bl[n], acc[m][n], 0, 0, 0);
                acc[m][n] = __builtin_amdgcn_mfma_f32_16x16x32_bf16(al, bh[n], acc[m][n], 0, 0, 0);
            }
        }
    }
    float csv[4];
#pragma unroll
    for (int n = 0; n < 4; n++) csv[n] = cs[col0 + wc * 64 + n * 16 + r];
#pragma unroll
    for (int m = 0; m < 4; m++)
#pragma unroll
        for (int n = 0; n < 4; n++)
#pragma unroll
            for (int j = 0; j < 4; j++) {
                size_t grow = row0 + wr * 64 + m * 16 + g * 4 + j;
                size_t gcol = col0 + wc * 64 + n * 16 + r;
                O[grow * D + gcol] = acc[m][n][j] * csv[n];
            }
}

extern "C" void kernel_launch(void* const* d_in, const int* in_sizes, int n_in,
                              void* d_out, int out_size, void* d_ws, size_t ws_size,
                              hipStream_t stream) {
    const float* x = (const float*)d_in[0];
    const float* W1 = (const float*)d_in[1];
    const float* b1 = (const float*)d_in[2];
    const float* W2 = (const float*)d_in[3];
    const float* b2 = (const float*)d_in[4];
    const float* W3 = (const float*)d_in[5];
    const float* b3 = (const float*)d_in[6];

    float* out = (float*)d_out;
    float* Rout = out + D;

    char* ws = (char*)d_ws;
    float* z1 = (float*)ws;
    float* z2 = z1 + D;
    float* z3 = z2 + D;
    float* a1 = z3 + D;
    float* a2 = a1 + D;
    float* s3 = a2 + D;
    float* g2 = s3 + D;
    float* g1 = g2 + D;
    size_t smallB = (size_t)D * 8 * sizeof(float);

    const size_t PL = (size_t)D * D;               // ushorts per plane
    size_t planesB = 3 * PL * sizeof(ushort);      // 96 MB
    size_t cB = (size_t)D * D * sizeof(float);     // 64 MB
    size_t tierNeed = smallB + planesB + cB + 256; // ~160.1 MB (proven available in R7)

    // forward pass — bit-exact numpy-f32 emulation (unchanged)
    gemv_blas8<<<(D * 8) / 256, 256, 0, stream>>>(W1, x, b1, z1, a1, 1);
    gemv_blas8<<<(D * 8) / 256, 256, 0, stream>>>(W2, a1, b2, z2, a2, 1);
    gemv_blas8<<<(D * 8) / 256, 256, 0, stream>>>(W3, a2, b3, z3, nullptr, 0);
    vecprep32<<<D / 256, 256, 0, stream>>>(z1, z2, z3, a1, a2, b3, out, s3, g2, g1);

    dim3 gg(D / 128, D / 128);
    if (ws_size >= tierNeed) {
        ushort* Bpl = (ushort*)(ws + smallB);
        float* C = (float*)(ws + smallB + planesB);
        int pgrid = (int)((PL / 8) / 256);
        prepBT<<<pgrid, 256, 0, stream>>>(W2, Bpl, Bpl + PL, Bpl + 2 * PL);
        gemm_bs<1><<<gg, 256, 0, stream>>>(W3, Bpl, Bpl + PL, Bpl + 2 * PL, s3, g2, g1, C);
        prepBT<<<pgrid, 256, 0, stream>>>(W1, Bpl, Bpl + PL, Bpl + 2 * PL);
        gemm_bs<0><<<gg, 256, 0, stream>>>(C, Bpl, Bpl + PL, Bpl + 2 * PL, nullptr, nullptr, x, Rout);
    } else {
        float* C = (float*)(ws + smallB);
        gemm3<1><<<gg, 256, 0, stream>>>(W3, W2, s3, g2, g1, C);
        gemm3<0><<<gg, 256, 0, stream>>>(C, W1, nullptr, nullptr, x, Rout);
    }
}